// Round 1
// baseline (214.359 us; speedup 1.0000x reference)
//
#include <hip/hip_runtime.h>
#include <hip/hip_bf16.h>

typedef __bf16 bf16x8 __attribute__((ext_vector_type(8)));
typedef __bf16 bf16x4 __attribute__((ext_vector_type(4)));
typedef float  f32x4  __attribute__((ext_vector_type(4)));

constexpr int BATCH = 2, H = 8, NQ = 1024, SEQ = 8192, DIM = 256, HD = 32;
constexpr float SCALE = 0.17677669529663687f;  // 32^-0.5

// workspace layout (bytes)
constexpr size_t OFF_QH  = 0;                                      // bf16 [B*H][NQ][32]
constexpr size_t OFF_KH  = OFF_QH  + (size_t)BATCH*H*NQ*HD*2;      // bf16 [B*H][S][32]
constexpr size_t OFF_VT  = OFF_KH  + (size_t)BATCH*H*SEQ*HD*2;     // bf16 [B*H][32][S]
constexpr size_t OFF_CTX = OFF_VT  + (size_t)BATCH*H*SEQ*HD*2;     // f32  [B*NQ][256]
constexpr size_t OFF_W   = OFF_CTX + (size_t)BATCH*NQ*DIM*4;       // bf16 4 x [256][256]

__global__ void prep_weights_kernel(const float* __restrict__ Wq, const float* __restrict__ Wk,
                                    const float* __restrict__ Wv, const float* __restrict__ Wo,
                                    __bf16* __restrict__ out) {
    int i = blockIdx.x * 256 + threadIdx.x;          // 65536 threads
    out[i]          = (__bf16)(Wq[i] * SCALE);       // fold q-scale into Wq
    out[65536 + i]  = (__bf16)(Wk[i]);
    out[131072 + i] = (__bf16)(Wv[i]);
    out[196608 + i] = (__bf16)(Wo[i]);
}

// Y = bf16(X[M x 256]) @ Wbf^T + bias.  Block: 64 rows x all 256 cols, 4 waves.
// MODE 0: bf16 head layout [b*H+h][row][hd]   (Q and K)
// MODE 1: bf16 transposed  [b*H+h][hd][row]   (V^T; MFMA operands swapped)
// MODE 2: f32 plain [m][n]                    (final output)
template<int MODE>
__global__ __launch_bounds__(256, 2)
void proj_kernel(const float* __restrict__ X, const __bf16* __restrict__ W,
                 const float* __restrict__ bias, float bias_scale,
                 void* __restrict__ outp, int Mb)
{
    __shared__ __bf16 Ash[64][40];    // 64 rows x 32 k (+8 pad)
    __shared__ __bf16 Bsh[256][40];   // 256 n  x 32 k (+8 pad)
    const int m0 = blockIdx.x * 64;
    const int t = threadIdx.x;
    const int w = t >> 6;
    const int lane = t & 63;
    const int g = lane >> 4;
    const int lr = lane & 15;

    f32x4 acc[4][4] = {};

    for (int kk = 0; kk < DIM; kk += 32) {
        __syncthreads();
        // stage A: 64x32 fp32 -> bf16 (512 float4 chunks)
        #pragma unroll
        for (int i = 0; i < 2; ++i) {
            int c = t * 2 + i;
            int row = c >> 3;
            int q = c & 7;
            const float4 v = *reinterpret_cast<const float4*>(X + (size_t)(m0 + row) * DIM + kk + q * 4);
            bf16x4 bv;
            bv[0] = (__bf16)v.x; bv[1] = (__bf16)v.y; bv[2] = (__bf16)v.z; bv[3] = (__bf16)v.w;
            *reinterpret_cast<bf16x4*>(&Ash[row][q * 4]) = bv;
        }
        // stage B: W[n][kk..kk+32) bf16 (1024 8-elem chunks)
        #pragma unroll
        for (int i = 0; i < 4; ++i) {
            int c = t * 4 + i;
            int n = c >> 2;
            int q = c & 3;
            *reinterpret_cast<bf16x8*>(&Bsh[n][q * 8]) =
                *reinterpret_cast<const bf16x8*>(W + (size_t)n * DIM + kk + q * 8);
        }
        __syncthreads();

        bf16x8 af[4], bfr[4];
        #pragma unroll
        for (int mt = 0; mt < 4; ++mt)
            af[mt] = *reinterpret_cast<const bf16x8*>(&Ash[mt * 16 + lr][g * 8]);
        #pragma unroll
        for (int nt = 0; nt < 4; ++nt)
            bfr[nt] = *reinterpret_cast<const bf16x8*>(&Bsh[w * 64 + nt * 16 + lr][g * 8]);
        #pragma unroll
        for (int mt = 0; mt < 4; ++mt)
            #pragma unroll
            for (int nt = 0; nt < 4; ++nt) {
                if (MODE == 1)
                    acc[mt][nt] = __builtin_amdgcn_mfma_f32_16x16x32_bf16(bfr[nt], af[mt], acc[mt][nt], 0, 0, 0);
                else
                    acc[mt][nt] = __builtin_amdgcn_mfma_f32_16x16x32_bf16(af[mt], bfr[nt], acc[mt][nt], 0, 0, 0);
            }
    }

    const int bb = m0 / Mb;            // whole block lies in one batch (64 | Mb)
    const int sbase = m0 - bb * Mb;

    if (MODE == 0) {
        __bf16* outb = (__bf16*)outp;
        #pragma unroll
        for (int nt = 0; nt < 4; ++nt) {
            int n = w * 64 + nt * 16 + lr;
            float bv = bias[n] * bias_scale;
            int h = n >> 5, hd = n & 31;
            __bf16* op = outb + ((size_t)(bb * H + h) * Mb) * 32 + hd;
            #pragma unroll
            for (int mt = 0; mt < 4; ++mt)
                #pragma unroll
                for (int r = 0; r < 4; ++r) {
                    int s = sbase + mt * 16 + g * 4 + r;
                    op[(size_t)s * 32] = (__bf16)(acc[mt][nt][r] + bv);
                }
        }
    } else if (MODE == 1) {
        __bf16* outb = (__bf16*)outp;
        #pragma unroll
        for (int nt = 0; nt < 4; ++nt)
            #pragma unroll
            for (int r = 0; r < 4; ++r) {
                int n = w * 64 + nt * 16 + g * 4 + r;   // D rows = n (operands swapped)
                float bv = bias[n] * bias_scale;
                int h = n >> 5, hd = n & 31;
                __bf16* op = outb + ((size_t)(bb * H + h) * 32 + hd) * SEQ;
                #pragma unroll
                for (int mt = 0; mt < 4; ++mt) {
                    int s = sbase + mt * 16 + lr;       // D cols = m (contiguous per 16 lanes)
                    op[s] = (__bf16)(acc[mt][nt][r] + bv);
                }
            }
    } else {
        float* outf = (float*)outp;
        #pragma unroll
        for (int nt = 0; nt < 4; ++nt) {
            int n = w * 64 + nt * 16 + lr;
            float bv = bias[n] * bias_scale;
            #pragma unroll
            for (int mt = 0; mt < 4; ++mt)
                #pragma unroll
                for (int r = 0; r < 4; ++r) {
                    int m = m0 + mt * 16 + g * 4 + r;
                    outf[(size_t)m * DIM + n] = acc[mt][nt][r] + bv;
                }
        }
    }
}

// Flash attention. Grid 256 = 16 (bh, low bits -> XCD locality) x 16 q-tiles of 64.
// Swapped QK^T: S^T = mfma(K_frag, Q_frag): lane owns q-row (lane&15), kpos = g*4+reg (+16).
__global__ __launch_bounds__(256, 1)
void attn_kernel(const __bf16* __restrict__ qh, const __bf16* __restrict__ kh,
                 const __bf16* __restrict__ vt, const float* __restrict__ mask,
                 float* __restrict__ ctx)
{
    const int bid = blockIdx.x;
    const int bh = bid & 15;
    const int qt = bid >> 4;
    const int b = bh >> 3, h = bh & 7;
    const int t = threadIdx.x;
    const int w = t >> 6, lane = t & 63, g = lane >> 4, lr = lane & 15;
    const int q0 = qt * 64 + w * 16;

    const bf16x8 qf = *reinterpret_cast<const bf16x8*>(qh + ((size_t)bh * NQ + q0 + lr) * HD + g * 8);
    const __bf16* kb = kh + (size_t)bh * SEQ * HD;
    const __bf16* vb = vt + (size_t)bh * HD * SEQ;
    const float* mb = mask + (size_t)b * SEQ;

    float m_run = -3.0e38f, l_run = 0.f;
    f32x4 o0 = {0.f, 0.f, 0.f, 0.f}, o1 = {0.f, 0.f, 0.f, 0.f};
    const f32x4 zero = {0.f, 0.f, 0.f, 0.f};

    for (int kv = 0; kv < SEQ; kv += 32) {
        bf16x8 kf0 = *reinterpret_cast<const bf16x8*>(kb + (size_t)(kv + lr) * HD + g * 8);
        bf16x8 kf1 = *reinterpret_cast<const bf16x8*>(kb + (size_t)(kv + 16 + lr) * HD + g * 8);
        f32x4 s0 = __builtin_amdgcn_mfma_f32_16x16x32_bf16(kf0, qf, zero, 0, 0, 0);
        f32x4 s1 = __builtin_amdgcn_mfma_f32_16x16x32_bf16(kf1, qf, zero, 0, 0, 0);

        const float4 mk0 = *reinterpret_cast<const float4*>(mb + kv + g * 4);
        const float4 mk1 = *reinterpret_cast<const float4*>(mb + kv + 16 + g * 4);
        s0[0] -= 100.f * mk0.x; s0[1] -= 100.f * mk0.y; s0[2] -= 100.f * mk0.z; s0[3] -= 100.f * mk0.w;
        s1[0] -= 100.f * mk1.x; s1[1] -= 100.f * mk1.y; s1[2] -= 100.f * mk1.z; s1[3] -= 100.f * mk1.w;

        float pm = fmaxf(fmaxf(fmaxf(s0[0], s0[1]), fmaxf(s0[2], s0[3])),
                         fmaxf(fmaxf(s1[0], s1[1]), fmaxf(s1[2], s1[3])));
        pm = fmaxf(pm, __shfl_xor(pm, 16));
        pm = fmaxf(pm, __shfl_xor(pm, 32));
        const float mnew = fmaxf(m_run, pm);
        const float scl = __expf(m_run - mnew);

        float p[8];
        #pragma unroll
        for (int r = 0; r < 4; ++r) { p[r] = __expf(s0[r] - mnew); p[4 + r] = __expf(s1[r] - mnew); }
        float ps = ((p[0] + p[1]) + (p[2] + p[3])) + ((p[4] + p[5]) + (p[6] + p[7]));
        ps += __shfl_xor(ps, 16);
        ps += __shfl_xor(ps, 32);
        l_run = l_run * scl + ps;
        #pragma unroll
        for (int r = 0; r < 4; ++r) { o0[r] *= scl; o1[r] *= scl; }

        bf16x8 pf;
        #pragma unroll
        for (int i = 0; i < 8; ++i) pf[i] = (__bf16)p[i];

        bf16x4 va0 = *reinterpret_cast<const bf16x4*>(vb + (size_t)lr * SEQ + kv + g * 4);
        bf16x4 va1 = *reinterpret_cast<const bf16x4*>(vb + (size_t)lr * SEQ + kv + 16 + g * 4);
        bf16x4 vc0 = *reinterpret_cast<const bf16x4*>(vb + (size_t)(16 + lr) * SEQ + kv + g * 4);
        bf16x4 vc1 = *reinterpret_cast<const bf16x4*>(vb + (size_t)(16 + lr) * SEQ + kv + 16 + g * 4);
        bf16x8 vf0 = __builtin_shufflevector(va0, va1, 0, 1, 2, 3, 4, 5, 6, 7);
        bf16x8 vf1 = __builtin_shufflevector(vc0, vc1, 0, 1, 2, 3, 4, 5, 6, 7);

        o0 = __builtin_amdgcn_mfma_f32_16x16x32_bf16(vf0, pf, o0, 0, 0, 0);
        o1 = __builtin_amdgcn_mfma_f32_16x16x32_bf16(vf1, pf, o1, 0, 0, 0);
        m_run = mnew;
    }

    const float inv = 1.f / l_run;
    float* cp = ctx + ((size_t)b * NQ + q0 + lr) * DIM + h * HD;
    #pragma unroll
    for (int r = 0; r < 4; ++r) {
        cp[g * 4 + r]      = o0[r] * inv;
        cp[16 + g * 4 + r] = o1[r] * inv;
    }
}

extern "C" void kernel_launch(void* const* d_in, const int* in_sizes, int n_in,
                              void* d_out, int out_size, void* d_ws, size_t ws_size,
                              hipStream_t stream)
{
    const float* Xq   = (const float*)d_in[0];
    const float* Xk   = (const float*)d_in[1];
    const float* Xv   = (const float*)d_in[2];
    const float* mask = (const float*)d_in[3];
    const float* Wq   = (const float*)d_in[4];
    const float* bq   = (const float*)d_in[5];
    const float* Wk   = (const float*)d_in[6];
    const float* bk   = (const float*)d_in[7];
    const float* Wv   = (const float*)d_in[8];
    const float* bv   = (const float*)d_in[9];
    const float* Wo   = (const float*)d_in[10];
    const float* bo   = (const float*)d_in[11];

    char* ws = (char*)d_ws;
    __bf16* qh  = (__bf16*)(ws + OFF_QH);
    __bf16* kh  = (__bf16*)(ws + OFF_KH);
    __bf16* vtp = (__bf16*)(ws + OFF_VT);
    float*  ctx = (float*)(ws + OFF_CTX);
    __bf16* Wb  = (__bf16*)(ws + OFF_W);

    prep_weights_kernel<<<256, 256, 0, stream>>>(Wq, Wk, Wv, Wo, Wb);
    proj_kernel<0><<<BATCH * NQ / 64, 256, 0, stream>>>(Xq, Wb,          bq, SCALE, qh,  NQ);
    proj_kernel<0><<<BATCH * SEQ / 64, 256, 0, stream>>>(Xk, Wb + 65536,  bk, 1.f,   kh,  SEQ);
    proj_kernel<1><<<BATCH * SEQ / 64, 256, 0, stream>>>(Xv, Wb + 131072, bv, 1.f,   vtp, SEQ);
    attn_kernel<<<256, 256, 0, stream>>>(qh, kh, vtp, mask, ctx);
    proj_kernel<2><<<BATCH * NQ / 64, 256, 0, stream>>>(ctx, Wb + 196608, bo, 1.f,   d_out, NQ);
}